// Round 9
// baseline (357.853 us; speedup 1.0000x reference)
//
#include <hip/hip_runtime.h>
#include <hip/hip_bf16.h>

// GCN 2-layer forward. CSR-by-dst on device; gather-side aggregation.
// Round 9: XCD-privatized histogram — 8 private counter copies indexed by
// blockIdx&7 (matches XCD round-robin), eliminating cross-XCD atomic
// line ping-pong. scan3 folds the 8-way combine + copyoff emission.

constexpr int SCAN_CHUNK = 1024;
constexpr int NCPY = 8;

__device__ __forceinline__ unsigned short f2bf(float f) {   // round-to-nearest-even
    unsigned u = __float_as_uint(f);
    return (unsigned short)((u + 0x7FFF + ((u >> 16) & 1)) >> 16);
}
__device__ __forceinline__ float bf2f(unsigned short b) {   // exact widening
    return __uint_as_float((unsigned)b << 16);
}

__global__ __launch_bounds__(256) void k_zero(int* __restrict__ p, long n) {
    long i = (long)blockIdx.x * 256 + threadIdx.x;
    if (i < n) p[i] = 0;
}

// cnt8[(bid&7)][dst]++ ; rank[e] = rank within (copy, node).
__global__ __launch_bounds__(256) void k_hist_rank8(const int* __restrict__ dst,
                                                    int* __restrict__ cnt8,
                                                    int* __restrict__ rank,
                                                    int N, int E) {
    int e = blockIdx.x * 256 + threadIdx.x;
    if (e >= E) return;
    const int c = blockIdx.x & (NCPY - 1);
    rank[e] = atomicAdd(&cnt8[(long)c * N + dst[e]], 1);
}

// per-block sums of total-degree chunks (summing the 8 copies inline)
__global__ __launch_bounds__(256) void k_scan1(const int* __restrict__ cnt8,
                                               int* __restrict__ bsum, int N) {
    __shared__ int sm[256];
    const int t = threadIdx.x;
    const long base = (long)blockIdx.x * SCAN_CHUNK + t * 4;
    int s = 0;
    #pragma unroll
    for (int k = 0; k < 4; ++k) {
        long i = base + k;
        if (i < N)
            #pragma unroll
            for (int c = 0; c < NCPY; ++c) s += cnt8[(long)c * N + i];
    }
    sm[t] = s; __syncthreads();
    for (int off = 128; off > 0; off >>= 1) {
        if (t < off) sm[t] += sm[t + off];
        __syncthreads();
    }
    if (t == 0) bsum[blockIdx.x] = sm[0];
}

// exclusive scan of block sums (nb <= 256)
__global__ __launch_bounds__(256) void k_scan2(const int* __restrict__ bsum,
                                               int* __restrict__ bofs, int nb) {
    __shared__ int sm[256];
    const int t = threadIdx.x;
    const int v = (t < nb) ? bsum[t] : 0;
    sm[t] = v; __syncthreads();
    for (int off = 1; off < 256; off <<= 1) {
        int u = (t >= off) ? sm[t - off] : 0;
        __syncthreads();
        sm[t] += u;
        __syncthreads();
    }
    if (t < nb) bofs[t] = sm[t] - v;
}

// per-element scan + deg/dinv + per-copy base offsets (copyoff = offs + prefix).
__global__ __launch_bounds__(256) void k_scan3(const int* __restrict__ cnt8,
                                               const int* __restrict__ bofs,
                                               int* __restrict__ offs,
                                               int* __restrict__ deg,
                                               int* __restrict__ copyoff,
                                               float* __restrict__ dinv, int N) {
    __shared__ int sm[256];
    const int t = threadIdx.x;
    const long base = (long)blockIdx.x * SCAN_CHUNK + t * 4;
    int c8[4][NCPY]; int tot[4]; int s = 0;
    #pragma unroll
    for (int k = 0; k < 4; ++k) {
        long i = base + k; tot[k] = 0;
        #pragma unroll
        for (int c = 0; c < NCPY; ++c) {
            c8[k][c] = (i < N) ? cnt8[(long)c * N + i] : 0;
            tot[k] += c8[k][c];
        }
        s += tot[k];
    }
    sm[t] = s; __syncthreads();
    for (int off = 1; off < 256; off <<= 1) {
        int u = (t >= off) ? sm[t - off] : 0;
        __syncthreads();
        sm[t] += u;
        __syncthreads();
    }
    int run = bofs[blockIdx.x] + (sm[t] - s);
    #pragma unroll
    for (int k = 0; k < 4; ++k) {
        long i = base + k;
        if (i < N) {
            offs[i] = run;
            deg[i]  = tot[k];
            dinv[i] = rsqrtf((float)tot[k] + 1.0f);
            int a = run;
            #pragma unroll
            for (int c = 0; c < NCPY; ++c) { copyoff[(long)c * N + i] = a; a += c8[k][c]; }
            run += tot[k];
        }
    }
}

// slots[copyoff[(bid&7)][dst] + rank] = src — atomic-free nt scatter store.
__global__ __launch_bounds__(256) void k_fill8(const int* __restrict__ src,
                                               const int* __restrict__ dst,
                                               const int* __restrict__ rank,
                                               const int* __restrict__ copyoff,
                                               int* __restrict__ slots,
                                               int N, int E) {
    int e = blockIdx.x * 256 + threadIdx.x;
    if (e >= E) return;
    const int c = blockIdx.x & (NCPY - 1);
    const int pos = copyoff[(long)c * N + dst[e]] + rank[e];
    __builtin_nontemporal_store(src[e], &slots[pos]);
}

// out[r][c] = sum_k f(A[r][k]) * W[k][c];  f = relu(x + bin[k]) if TRANS_IN.
// A fp32; out bf16.
template<int IN_C, int OUT_C, bool TRANS_IN>
__global__ __launch_bounds__(256) void k_mm(const float* __restrict__ A,
                                            const float* __restrict__ W,
                                            const float* __restrict__ bin,
                                            unsigned short* __restrict__ out,
                                            int n_rows) {
    constexpr int C4   = OUT_C / 4;
    constexpr int ROWS = 256 / C4;
    __shared__ float Ws[IN_C][OUT_C];
    __shared__ float xs[ROWS][IN_C + 1];
    __shared__ float bs[IN_C];

    const int tid = threadIdx.x;
    for (int i = tid; i < IN_C * OUT_C; i += 256)
        Ws[i / OUT_C][i % OUT_C] = W[i];
    if (tid < IN_C) bs[tid] = TRANS_IN ? bin[tid] : 0.0f;

    const int c4 = (tid % C4) * 4;
    const int rl = tid / C4;
    const int tiles = (n_rows + ROWS - 1) / ROWS;

    for (int t = blockIdx.x; t < tiles; t += gridDim.x) {
        const int r0 = t * ROWS;
        __syncthreads();
        for (int i = tid; i < ROWS * IN_C; i += 256) {
            int r = i / IN_C, k = i % IN_C;
            float v = 0.0f;
            if (r0 + r < n_rows) {
                v = A[(long)(r0 + r) * IN_C + k];
                if (TRANS_IN) v = fmaxf(v + bs[k], 0.0f);
            }
            xs[r][k] = v;
        }
        __syncthreads();

        float4 acc = {0.f, 0.f, 0.f, 0.f};
        #pragma unroll
        for (int k = 0; k < IN_C; ++k) {
            const float a = xs[rl][k];
            const float4 w4 = *reinterpret_cast<const float4*>(&Ws[k][c4]);
            acc.x += a * w4.x; acc.y += a * w4.y;
            acc.z += a * w4.z; acc.w += a * w4.w;
        }
        const int row = r0 + rl;
        if (row < n_rows) {
            ushort4 o;
            o.x = f2bf(acc.x); o.y = f2bf(acc.y);
            o.z = f2bf(acc.z); o.w = f2bf(acc.w);
            *reinterpret_cast<ushort4*>(&out[(long)row * OUT_C + c4]) = o;
        }
    }
}

// One wave per node, F=64: 4 groups x 16 lanes; 4 edges/iter, bf16x4 gathers.
__global__ __launch_bounds__(256) void k_agg64(const int* __restrict__ offs,
                                               const int* __restrict__ deg,
                                               const int* __restrict__ slots,
                                               const float* __restrict__ dinv,
                                               const unsigned short* __restrict__ h,
                                               float* __restrict__ agg, int N) {
    const int wid  = threadIdx.x >> 6;
    const int lane = threadIdx.x & 63;
    const int grp  = lane >> 4;
    const int c4   = (lane & 15) * 4;
    const int node = blockIdx.x * 4 + wid;
    if (node >= N) return;
    const int beg = offs[node], dg = deg[node];
    const float dd = dinv[node];
    float4 acc = {0.f, 0.f, 0.f, 0.f};
    for (int j0 = 0; j0 < dg; j0 += 64) {
        const int m = min(64, dg - j0);
        int sv = 0; float dv = 0.f;
        if (lane < m) { sv = slots[beg + j0 + lane]; dv = dinv[sv]; }
        #pragma unroll 4
        for (int jj = 0; jj < m; jj += 4) {
            const int idx = jj + grp;
            const int   s = __shfl(sv, idx);
            const float w = __shfl(dv, idx) * dd;
            if (idx < m) {
                const ushort4 hv = *reinterpret_cast<const ushort4*>(&h[(long)s * 64 + c4]);
                acc.x += w * bf2f(hv.x); acc.y += w * bf2f(hv.y);
                acc.z += w * bf2f(hv.z); acc.w += w * bf2f(hv.w);
            }
        }
    }
    #pragma unroll
    for (int off = 16; off <= 32; off <<= 1) {
        acc.x += __shfl_xor(acc.x, off); acc.y += __shfl_xor(acc.y, off);
        acc.z += __shfl_xor(acc.z, off); acc.w += __shfl_xor(acc.w, off);
    }
    if (lane < 16) {
        const ushort4 hv = *reinterpret_cast<const ushort4*>(&h[(long)node * 64 + c4]);
        const float w = dd * dd;
        acc.x += w * bf2f(hv.x); acc.y += w * bf2f(hv.y);
        acc.z += w * bf2f(hv.z); acc.w += w * bf2f(hv.w);
        *reinterpret_cast<float4*>(&agg[(long)node * 64 + c4]) = acc;
    }
}

// One wave per node, F=32: 8 groups x 8 lanes; 8 edges/iter, bf16x4 gathers.
// Fuses self-loop + bias + log_softmax; writes d_out (fp32).
__global__ __launch_bounds__(256) void k_agg32_lsm(const int* __restrict__ offs,
                                                   const int* __restrict__ deg,
                                                   const int* __restrict__ slots,
                                                   const float* __restrict__ dinv,
                                                   const unsigned short* __restrict__ h,
                                                   const float* __restrict__ b2,
                                                   float* __restrict__ out, int N) {
    const int wid  = threadIdx.x >> 6;
    const int lane = threadIdx.x & 63;
    const int grp  = lane >> 3;
    const int c4   = (lane & 7) * 4;
    const int node = blockIdx.x * 4 + wid;
    if (node >= N) return;
    const int beg = offs[node], dg = deg[node];
    const float dd = dinv[node];
    float4 acc = {0.f, 0.f, 0.f, 0.f};
    for (int j0 = 0; j0 < dg; j0 += 64) {
        const int m = min(64, dg - j0);
        int sv = 0; float dv = 0.f;
        if (lane < m) { sv = slots[beg + j0 + lane]; dv = dinv[sv]; }
        #pragma unroll 2
        for (int jj = 0; jj < m; jj += 8) {
            const int idx = jj + grp;
            const int   s = __shfl(sv, idx);
            const float w = __shfl(dv, idx) * dd;
            if (idx < m) {
                const ushort4 hv = *reinterpret_cast<const ushort4*>(&h[(long)s * 32 + c4]);
                acc.x += w * bf2f(hv.x); acc.y += w * bf2f(hv.y);
                acc.z += w * bf2f(hv.z); acc.w += w * bf2f(hv.w);
            }
        }
    }
    #pragma unroll
    for (int off = 8; off <= 32; off <<= 1) {
        acc.x += __shfl_xor(acc.x, off); acc.y += __shfl_xor(acc.y, off);
        acc.z += __shfl_xor(acc.z, off); acc.w += __shfl_xor(acc.w, off);
    }
    const ushort4 hv = *reinterpret_cast<const ushort4*>(&h[(long)node * 32 + c4]);
    const float4 bv = *reinterpret_cast<const float4*>(&b2[c4]);
    const float w = dd * dd;
    float4 v;
    v.x = acc.x + w * bf2f(hv.x) + bv.x; v.y = acc.y + w * bf2f(hv.y) + bv.y;
    v.z = acc.z + w * bf2f(hv.z) + bv.z; v.w = acc.w + w * bf2f(hv.w) + bv.w;
    float mx = fmaxf(fmaxf(v.x, v.y), fmaxf(v.z, v.w));
    #pragma unroll
    for (int off = 1; off < 8; off <<= 1) mx = fmaxf(mx, __shfl_xor(mx, off));
    float4 ev;
    ev.x = __expf(v.x - mx); ev.y = __expf(v.y - mx);
    ev.z = __expf(v.z - mx); ev.w = __expf(v.w - mx);
    float ss = ev.x + ev.y + ev.z + ev.w;
    #pragma unroll
    for (int off = 1; off < 8; off <<= 1) ss += __shfl_xor(ss, off);
    const float lg = mx + __logf(ss);
    if (lane < 8) {
        float4 o;
        o.x = v.x - lg; o.y = v.y - lg; o.z = v.z - lg; o.w = v.w - lg;
        *reinterpret_cast<float4*>(&out[(long)node * 32 + c4]) = o;
    }
}

extern "C" void kernel_launch(void* const* d_in, const int* in_sizes, int n_in,
                              void* d_out, int out_size, void* d_ws, size_t ws_size,
                              hipStream_t stream) {
    const float* x  = (const float*)d_in[0];
    const int*   ei = (const int*)  d_in[1];
    const float* W1 = (const float*)d_in[2];
    const float* b1 = (const float*)d_in[3];
    const float* W2 = (const float*)d_in[4];
    const float* b2 = (const float*)d_in[5];
    float* out = (float*)d_out;

    const int N = in_sizes[0] / 64;      // 100000
    const int E = in_sizes[1] / 2;       // 1600000
    const int* src = ei;
    const int* dst = ei + E;

    // workspace layout (element offsets in 4B units, 256B-aligned blocks)
    auto align = [](long v) { return (v + 63) & ~63L; };
    char* wsb = (char*)d_ws;
    long o = 0;
    int*   cnt8    = (int*)(wsb + o * 4); o = align(o + (long)NCPY * N);
    int*   copyoff = (int*)(wsb + o * 4); o = align(o + (long)NCPY * N);
    int*   offs    = (int*)(wsb + o * 4); o = align(o + N);
    int*   deg     = (int*)(wsb + o * 4); o = align(o + N);
    int*   bsum    = (int*)(wsb + o * 4); o = align(o + 256);
    int*   bofs    = (int*)(wsb + o * 4); o = align(o + 256);
    float* dinv    = (float*)(wsb + o * 4); o = align(o + N);
    int*   slots   = (int*)(wsb + o * 4); o = align(o + E);
    unsigned short* h1 = (unsigned short*)(wsb + o * 4); o = align(o + (long)N * 32); // bf16 N*64
    float* agg1    = (float*)(wsb + o * 4); o = align(o + (long)N * 64);
    unsigned short* h2 = h1;             // bf16 N*32, reuse after agg64 consumes h1
    int*   rank    = (int*)h1;           // overlay: E ints (6.4MB) <= h1 (12.8MB); dead before k_mm

    const int B = 256;
    auto cdiv = [](long a, long b) { return (int)((a + b - 1) / b); };
    const int nb = cdiv(N, SCAN_CHUNK);   // 98 <= 256

    // CSR build + dinv (XCD-privatized histogram)
    k_zero      <<<cdiv((long)NCPY * N, B), B, 0, stream>>>(cnt8, (long)NCPY * N);
    k_hist_rank8<<<cdiv(E, B), B, 0, stream>>>(dst, cnt8, rank, N, E);
    k_scan1     <<<nb, B, 0, stream>>>(cnt8, bsum, N);
    k_scan2     <<<1,  B, 0, stream>>>(bsum, bofs, nb);
    k_scan3     <<<nb, B, 0, stream>>>(cnt8, bofs, offs, deg, copyoff, dinv, N);
    k_fill8     <<<cdiv(E, B), B, 0, stream>>>(src, dst, rank, copyoff, slots, N, E);

    // layer 1
    k_mm<64, 64, false><<<2048, B, 0, stream>>>(x, W1, b1, h1, N);
    k_agg64<<<cdiv(N, 4), B, 0, stream>>>(offs, deg, slots, dinv, h1, agg1, N);

    // layer 2
    k_mm<64, 32, true><<<2048, B, 0, stream>>>(agg1, W2, b1, h2, N);
    k_agg32_lsm<<<cdiv(N, 4), B, 0, stream>>>(offs, deg, slots, dinv, h2, b2, out, N);
}

// Round 12
// 312.101 us; speedup vs baseline: 1.1466x; 1.1466x over previous
//
#include <hip/hip_runtime.h>
#include <hip/hip_bf16.h>

// GCN 2-layer forward. Round 10: atomic-free CSR build via two-level counting
// sort (coarse bucket = dst>>6, 64 nodes/bucket; LDS atomics only). Proven
// mm/agg kernels unchanged. Requires N < 131072 (src packed in 17 bits).

constexpr int NBP     = 2048;    // padded bucket count (N/64 <= 2048)
constexpr int CHUNK   = 16384;   // edges per block in bucket passes

__device__ __forceinline__ unsigned short f2bf(float f) {   // round-to-nearest-even
    unsigned u = __float_as_uint(f);
    return (unsigned short)((u + 0x7FFF + ((u >> 16) & 1)) >> 16);
}
__device__ __forceinline__ float bf2f(unsigned short b) {   // exact widening
    return __uint_as_float((unsigned)b << 16);
}

// P1: per-block LDS histogram of coarse buckets -> counts[blk][NBP] (coalesced).
__global__ __launch_bounds__(256) void k_bhist(const int* __restrict__ dst,
                                               int* __restrict__ counts, int E) {
    __shared__ int hist[NBP];
    const int t = threadIdx.x, blk = blockIdx.x;
    for (int i = t; i < NBP; i += 256) hist[i] = 0;
    __syncthreads();
    const long e0 = (long)blk * CHUNK;
    for (int i = t; i < CHUNK; i += 256) {
        long e = e0 + i;
        if (e < E) atomicAdd(&hist[dst[e] >> 6], 1);
    }
    __syncthreads();
    for (int i = t; i < NBP; i += 256) counts[(long)blk * NBP + i] = hist[i];
}

// P2a: total[b] = sum over blocks of counts[blk][b].
__global__ __launch_bounds__(256) void k_btot(const int* __restrict__ counts,
                                              int* __restrict__ total, int nblk) {
    __shared__ int sm[256];
    const int t = threadIdx.x, b = blockIdx.x;
    int s = 0;
    for (int r = t; r < nblk; r += 256) s += counts[(long)r * NBP + b];
    sm[t] = s; __syncthreads();
    for (int off = 128; off > 0; off >>= 1) {
        if (t < off) sm[t] += sm[t + off];
        __syncthreads();
    }
    if (t == 0) total[b] = sm[0];
}

// P2b: exclusive scan of total[0..NBP) -> bbase (single block).
__global__ __launch_bounds__(256) void k_bscan(const int* __restrict__ total,
                                               int* __restrict__ bbase) {
    __shared__ int sm[256];
    const int t = threadIdx.x;
    int v[NBP / 256]; int s = 0;
    #pragma unroll
    for (int k = 0; k < NBP / 256; ++k) { v[k] = total[t * (NBP / 256) + k]; s += v[k]; }
    sm[t] = s; __syncthreads();
    for (int off = 1; off < 256; off <<= 1) {
        int u = (t >= off) ? sm[t - off] : 0;
        __syncthreads();
        sm[t] += u;
        __syncthreads();
    }
    int run = sm[t] - s;
    #pragma unroll
    for (int k = 0; k < NBP / 256; ++k) { bbase[t * (NBP / 256) + k] = run; run += v[k]; }
}

// P2c: per-bucket scan across blocks -> baseT[b][blk] (bucket-major, coalesced
// writes). Assumes nblk <= 256 (E <= 4.19M edges).
__global__ __launch_bounds__(256) void k_bbase(const int* __restrict__ counts,
                                               const int* __restrict__ bbase,
                                               int* __restrict__ baseT, int nblk) {
    __shared__ int sm[256];
    const int t = threadIdx.x, b = blockIdx.x;
    const int v = (t < nblk) ? counts[(long)t * NBP + b] : 0;
    sm[t] = v; __syncthreads();
    for (int off = 1; off < 256; off <<= 1) {
        int u = (t >= off) ? sm[t - off] : 0;
        __syncthreads();
        sm[t] += u;
        __syncthreads();
    }
    if (t < nblk) baseT[(long)b * nblk + t] = bbase[b] + sm[t] - v;
}

// P3: scatter packed (dstLow<<17 | src) into bucket-sorted ebuf.
// Per-(block,bucket) positions are contiguous runs -> lines fill in L2.
__global__ __launch_bounds__(256) void k_bscatter(const int* __restrict__ src,
                                                  const int* __restrict__ dst,
                                                  const int* __restrict__ baseT,
                                                  int* __restrict__ ebuf,
                                                  int E, int nblk) {
    __shared__ int cur[NBP];
    const int t = threadIdx.x, blk = blockIdx.x;
    for (int i = t; i < NBP; i += 256) cur[i] = baseT[(long)i * nblk + blk];
    __syncthreads();
    const long e0 = (long)blk * CHUNK;
    for (int i = t; i < CHUNK; i += 256) {
        long e = e0 + i;
        if (e < E) {
            const int d = dst[e];
            const int pos = atomicAdd(&cur[d >> 6], 1);
            ebuf[pos] = ((d & 63) << 17) | src[e];
        }
    }
}

// P4: per-bucket fine CSR in LDS -> slots (node-sorted), offs, deg, dinv.
__global__ __launch_bounds__(256) void k_bcsr(const int* __restrict__ ebuf,
                                              const int* __restrict__ total,
                                              const int* __restrict__ bbase,
                                              int* __restrict__ slots,
                                              int* __restrict__ offs,
                                              int* __restrict__ deg,
                                              float* __restrict__ dinv, int N) {
    const int b = blockIdx.x;
    const int node0 = b << 6;
    if (node0 >= N) return;
    const int t = threadIdx.x;
    __shared__ int cnt[64], loff[64], cur[64];
    const int nE = total[b], base = bbase[b];
    if (t < 64) cnt[t] = 0;
    __syncthreads();
    for (int i = t; i < nE; i += 256) atomicAdd(&cnt[ebuf[base + i] >> 17], 1);
    __syncthreads();
    if (t == 0) {
        int r = 0;
        for (int n = 0; n < 64; ++n) { loff[n] = r; cur[n] = r; r += cnt[n]; }
    }
    __syncthreads();
    for (int i = t; i < nE; i += 256) {
        const int p = ebuf[base + i];
        const int pos = atomicAdd(&cur[p >> 17], 1);
        slots[base + pos] = p & 0x1FFFF;   // runs of ~deg per node: L2 accumulates lines
    }
    if (t < 64) {
        const int node = node0 + t;
        if (node < N) {
            offs[node] = base + loff[t];
            deg[node]  = cnt[t];
            dinv[node] = rsqrtf((float)cnt[t] + 1.0f);
        }
    }
}

// out[r][c] = sum_k f(A[r][k]) * W[k][c];  f = relu(x + bin[k]) if TRANS_IN.
// A fp32; out bf16.
template<int IN_C, int OUT_C, bool TRANS_IN>
__global__ __launch_bounds__(256) void k_mm(const float* __restrict__ A,
                                            const float* __restrict__ W,
                                            const float* __restrict__ bin,
                                            unsigned short* __restrict__ out,
                                            int n_rows) {
    constexpr int C4   = OUT_C / 4;
    constexpr int ROWS = 256 / C4;
    __shared__ float Ws[IN_C][OUT_C];
    __shared__ float xs[ROWS][IN_C + 1];
    __shared__ float bs[IN_C];

    const int tid = threadIdx.x;
    for (int i = tid; i < IN_C * OUT_C; i += 256)
        Ws[i / OUT_C][i % OUT_C] = W[i];
    if (tid < IN_C) bs[tid] = TRANS_IN ? bin[tid] : 0.0f;

    const int c4 = (tid % C4) * 4;
    const int rl = tid / C4;
    const int tiles = (n_rows + ROWS - 1) / ROWS;

    for (int t = blockIdx.x; t < tiles; t += gridDim.x) {
        const int r0 = t * ROWS;
        __syncthreads();
        for (int i = tid; i < ROWS * IN_C; i += 256) {
            int r = i / IN_C, k = i % IN_C;
            float v = 0.0f;
            if (r0 + r < n_rows) {
                v = A[(long)(r0 + r) * IN_C + k];
                if (TRANS_IN) v = fmaxf(v + bs[k], 0.0f);
            }
            xs[r][k] = v;
        }
        __syncthreads();

        float4 acc = {0.f, 0.f, 0.f, 0.f};
        #pragma unroll
        for (int k = 0; k < IN_C; ++k) {
            const float a = xs[rl][k];
            const float4 w4 = *reinterpret_cast<const float4*>(&Ws[k][c4]);
            acc.x += a * w4.x; acc.y += a * w4.y;
            acc.z += a * w4.z; acc.w += a * w4.w;
        }
        const int row = r0 + rl;
        if (row < n_rows) {
            ushort4 o;
            o.x = f2bf(acc.x); o.y = f2bf(acc.y);
            o.z = f2bf(acc.z); o.w = f2bf(acc.w);
            *reinterpret_cast<ushort4*>(&out[(long)row * OUT_C + c4]) = o;
        }
    }
}

// One wave per node, F=64: 4 groups x 16 lanes; 4 edges/iter, bf16x4 gathers.
__global__ __launch_bounds__(256) void k_agg64(const int* __restrict__ offs,
                                               const int* __restrict__ deg,
                                               const int* __restrict__ slots,
                                               const float* __restrict__ dinv,
                                               const unsigned short* __restrict__ h,
                                               float* __restrict__ agg, int N) {
    const int wid  = threadIdx.x >> 6;
    const int lane = threadIdx.x & 63;
    const int grp  = lane >> 4;
    const int c4   = (lane & 15) * 4;
    const int node = blockIdx.x * 4 + wid;
    if (node >= N) return;
    const int beg = offs[node], dg = deg[node];
    const float dd = dinv[node];
    float4 acc = {0.f, 0.f, 0.f, 0.f};
    for (int j0 = 0; j0 < dg; j0 += 64) {
        const int m = min(64, dg - j0);
        int sv = 0; float dv = 0.f;
        if (lane < m) { sv = slots[beg + j0 + lane]; dv = dinv[sv]; }
        #pragma unroll 4
        for (int jj = 0; jj < m; jj += 4) {
            const int idx = jj + grp;
            const int   s = __shfl(sv, idx);
            const float w = __shfl(dv, idx) * dd;
            if (idx < m) {
                const ushort4 hv = *reinterpret_cast<const ushort4*>(&h[(long)s * 64 + c4]);
                acc.x += w * bf2f(hv.x); acc.y += w * bf2f(hv.y);
                acc.z += w * bf2f(hv.z); acc.w += w * bf2f(hv.w);
            }
        }
    }
    #pragma unroll
    for (int off = 16; off <= 32; off <<= 1) {
        acc.x += __shfl_xor(acc.x, off); acc.y += __shfl_xor(acc.y, off);
        acc.z += __shfl_xor(acc.z, off); acc.w += __shfl_xor(acc.w, off);
    }
    if (lane < 16) {
        const ushort4 hv = *reinterpret_cast<const ushort4*>(&h[(long)node * 64 + c4]);
        const float w = dd * dd;
        acc.x += w * bf2f(hv.x); acc.y += w * bf2f(hv.y);
        acc.z += w * bf2f(hv.z); acc.w += w * bf2f(hv.w);
        *reinterpret_cast<float4*>(&agg[(long)node * 64 + c4]) = acc;
    }
}

// One wave per node, F=32: 8 groups x 8 lanes; 8 edges/iter, bf16x4 gathers.
// Fuses self-loop + bias + log_softmax; writes d_out (fp32).
__global__ __launch_bounds__(256) void k_agg32_lsm(const int* __restrict__ offs,
                                                   const int* __restrict__ deg,
                                                   const int* __restrict__ slots,
                                                   const float* __restrict__ dinv,
                                                   const unsigned short* __restrict__ h,
                                                   const float* __restrict__ b2,
                                                   float* __restrict__ out, int N) {
    const int wid  = threadIdx.x >> 6;
    const int lane = threadIdx.x & 63;
    const int grp  = lane >> 3;
    const int c4   = (lane & 7) * 4;
    const int node = blockIdx.x * 4 + wid;
    if (node >= N) return;
    const int beg = offs[node], dg = deg[node];
    const float dd = dinv[node];
    float4 acc = {0.f, 0.f, 0.f, 0.f};
    for (int j0 = 0; j0 < dg; j0 += 64) {
        const int m = min(64, dg - j0);
        int sv = 0; float dv = 0.f;
        if (lane < m) { sv = slots[beg + j0 + lane]; dv = dinv[sv]; }
        #pragma unroll 2
        for (int jj = 0; jj < m; jj += 8) {
            const int idx = jj + grp;
            const int   s = __shfl(sv, idx);
            const float w = __shfl(dv, idx) * dd;
            if (idx < m) {
                const ushort4 hv = *reinterpret_cast<const ushort4*>(&h[(long)s * 32 + c4]);
                acc.x += w * bf2f(hv.x); acc.y += w * bf2f(hv.y);
                acc.z += w * bf2f(hv.z); acc.w += w * bf2f(hv.w);
            }
        }
    }
    #pragma unroll
    for (int off = 8; off <= 32; off <<= 1) {
        acc.x += __shfl_xor(acc.x, off); acc.y += __shfl_xor(acc.y, off);
        acc.z += __shfl_xor(acc.z, off); acc.w += __shfl_xor(acc.w, off);
    }
    const ushort4 hv = *reinterpret_cast<const ushort4*>(&h[(long)node * 32 + c4]);
    const float4 bv = *reinterpret_cast<const float4*>(&b2[c4]);
    const float w = dd * dd;
    float4 v;
    v.x = acc.x + w * bf2f(hv.x) + bv.x; v.y = acc.y + w * bf2f(hv.y) + bv.y;
    v.z = acc.z + w * bf2f(hv.z) + bv.z; v.w = acc.w + w * bf2f(hv.w) + bv.w;
    float mx = fmaxf(fmaxf(v.x, v.y), fmaxf(v.z, v.w));
    #pragma unroll
    for (int off = 1; off < 8; off <<= 1) mx = fmaxf(mx, __shfl_xor(mx, off));
    float4 ev;
    ev.x = __expf(v.x - mx); ev.y = __expf(v.y - mx);
    ev.z = __expf(v.z - mx); ev.w = __expf(v.w - mx);
    float ss = ev.x + ev.y + ev.z + ev.w;
    #pragma unroll
    for (int off = 1; off < 8; off <<= 1) ss += __shfl_xor(ss, off);
    const float lg = mx + __logf(ss);
    if (lane < 8) {
        float4 o;
        o.x = v.x - lg; o.y = v.y - lg; o.z = v.z - lg; o.w = v.w - lg;
        *reinterpret_cast<float4*>(&out[(long)node * 32 + c4]) = o;
    }
}

extern "C" void kernel_launch(void* const* d_in, const int* in_sizes, int n_in,
                              void* d_out, int out_size, void* d_ws, size_t ws_size,
                              hipStream_t stream) {
    const float* x  = (const float*)d_in[0];
    const int*   ei = (const int*)  d_in[1];
    const float* W1 = (const float*)d_in[2];
    const float* b1 = (const float*)d_in[3];
    const float* W2 = (const float*)d_in[4];
    const float* b2 = (const float*)d_in[5];
    float* out = (float*)d_out;

    const int N = in_sizes[0] / 64;      // 100000  (< 131072 for 17-bit packing)
    const int E = in_sizes[1] / 2;       // 1600000 (nblk <= 256)
    const int* src = ei;
    const int* dst = ei + E;

    auto cdiv = [](long a, long b) { return (int)((a + b - 1) / b); };
    const int nblk = cdiv(E, CHUNK);     // 98

    // workspace layout (element offsets in 4B units, 256B-aligned blocks)
    auto align = [](long v) { return (v + 63) & ~63L; };
    char* wsb = (char*)d_ws;
    long o = 0;
    int*   counts = (int*)(wsb + o * 4); o = align(o + (long)nblk * NBP);
    int*   total  = (int*)(wsb + o * 4); o = align(o + NBP);
    int*   bbase  = (int*)(wsb + o * 4); o = align(o + NBP);
    int*   baseT  = (int*)(wsb + o * 4); o = align(o + (long)NBP * nblk);
    int*   ebuf   = (int*)(wsb + o * 4); o = align(o + E);
    int*   slots  = (int*)(wsb + o * 4); o = align(o + E);
    int*   offs   = (int*)(wsb + o * 4); o = align(o + N);
    int*   deg    = (int*)(wsb + o * 4); o = align(o + N);
    float* dinv   = (float*)(wsb + o * 4); o = align(o + N);
    unsigned short* h1 = (unsigned short*)(wsb + o * 4); o = align(o + (long)N * 32); // bf16 N*64
    float* agg1   = (float*)(wsb + o * 4); o = align(o + (long)N * 64);
    unsigned short* h2 = h1;             // bf16 N*32, reuse after agg64 consumes h1

    const int B = 256;

    // atomic-free CSR build (two-level counting sort)
    k_bhist   <<<nblk, B, 0, stream>>>(dst, counts, E);
    k_btot    <<<NBP,  B, 0, stream>>>(counts, total, nblk);
    k_bscan   <<<1,    B, 0, stream>>>(total, bbase);
    k_bbase   <<<NBP,  B, 0, stream>>>(counts, bbase, baseT, nblk);
    k_bscatter<<<nblk, B, 0, stream>>>(src, dst, baseT, ebuf, E, nblk);
    k_bcsr    <<<NBP,  B, 0, stream>>>(ebuf, total, bbase, slots, offs, deg, dinv, N);

    // layer 1
    k_mm<64, 64, false><<<2048, B, 0, stream>>>(x, W1, b1, h1, N);
    k_agg64<<<cdiv(N, 4), B, 0, stream>>>(offs, deg, slots, dinv, h1, agg1, N);

    // layer 2
    k_mm<64, 32, true><<<2048, B, 0, stream>>>(agg1, W2, b1, h2, N);
    k_agg32_lsm<<<cdiv(N, 4), B, 0, stream>>>(offs, deg, slots, dinv, h2, b2, out, N);
}